// Round 1
// baseline (534.913 us; speedup 1.0000x reference)
//
#include <hip/hip_runtime.h>
#include <hip/hip_bf16.h>
#include <cstdint>
#include <cstddef>

#define AS1 __attribute__((address_space(1)))
#define AS3 __attribute__((address_space(3)))

typedef __bf16 bf16x8 __attribute__((ext_vector_type(8)));
typedef float  floatx4 __attribute__((ext_vector_type(4)));

__device__ __forceinline__ void load_lds16(const void* g, void* l) {
    // async global->LDS, 16B/lane; LDS dest is wave-uniform base + lane*16
    __builtin_amdgcn_global_load_lds((AS1 void*)g, (AS3 void*)l, 16, 0, 0);
}

__device__ __forceinline__ float fexp2(float x) { return __builtin_amdgcn_exp2f(x); }
__device__ __forceinline__ float flog2(float x) { return __builtin_amdgcn_logf(x); }

// ---------------------------------------------------------------------------
// Prep: apply MADE mask + convert fp32 -> bf16.
// mode 0: W0  keep = (row%127 >= col)
// mode 1: W1/W2 keep = (row%127 >= col%127)
// mode 2: W3  keep = ((row>>5) > col%127)      (i-1 >= deg  <=>  i > deg)
// mode 3: plain copy (x)
// n divisible by 256, cols = 1<<shift.
// ---------------------------------------------------------------------------
__global__ void prep_w(const float* __restrict__ W, __bf16* __restrict__ out,
                       int shift, int mode) {
    int idx = blockIdx.x * 256 + threadIdx.x;
    int row = idx >> shift;
    int col = idx & ((1 << shift) - 1);
    float v = W[idx];
    bool keep = true;
    if (mode == 0)      keep = (row % 127) >= col;
    else if (mode == 1) keep = (row % 127) >= (col % 127);
    else if (mode == 2) keep = (row >> 5) > (col % 127);
    out[idx] = (__bf16)(keep ? v : 0.0f);
}

// ---------------------------------------------------------------------------
// bf16 MFMA GEMM, C[M,N] = A[M,K] * Bw[N,K]^T + bias, optional ReLU.
// M fixed 8192 via grid.x=64. 128x128 tile, BK=32, 4 waves (2x2 of 64x64),
// 16x16x32 MFMA 4x4 per wave. global_load_lds width=16 staging, XOR-swizzled
// LDS 16B slots so frag ds_read_b128 is 2-way (free) on banks.
// ---------------------------------------------------------------------------
template <bool RELU, bool OBF16>
__global__ __launch_bounds__(256, 2)
void gemm_bt(const __bf16* __restrict__ A, const __bf16* __restrict__ Bw,
             const float* __restrict__ bias, void* __restrict__ Cout,
             int N, int K)
{
    __shared__ __align__(16) __bf16 lsA[128 * 32];
    __shared__ __align__(16) __bf16 lsB[128 * 32];
    const int tid  = threadIdx.x;
    const int wave = tid >> 6;
    const int lane = tid & 63;
    const int bm = blockIdx.x, bn = blockIdx.y;
    const int wm = wave >> 1, wn = wave & 1;

    // ---- staging setup: 16 chunks of 1KB (A:0..7, B:8..15), 4 per wave.
    // chunk j covers tile rows [16j,16j+16); lane l -> row 16j + (l>>2),
    // col-slot l&3 holds global col-block (l&3) ^ ((l>>3)&3)  (XOR swizzle).
    const int rsub = lane >> 2;
    const int cbx  = (lane & 3) ^ ((lane >> 3) & 3);
    const __bf16* gsrc[4];
    __bf16* ldst[4];
#pragma unroll
    for (int t = 0; t < 4; ++t) {
        int j = wave * 4 + t;
        if (j < 8) {
            int row = bm * 128 + j * 16 + rsub;
            gsrc[t] = A + (size_t)row * K + cbx * 8;
            ldst[t] = lsA + j * 512;
        } else {
            int jj = j - 8;
            int row = bn * 128 + jj * 16 + rsub;
            gsrc[t] = Bw + (size_t)row * K + cbx * 8;
            ldst[t] = lsB + jj * 512;
        }
    }

    // ---- frag read pointers (fixed per lane; single-buffered LDS)
    // A-frag layout: m = lane&15, k = (lane>>4)*8 + j ; same for B (n = lane&15).
    const int fr   = lane & 15;
    const int ks   = lane >> 4;
    const int slot = ks ^ ((fr >> 1) & 3);   // undo XOR swizzle
    const __bf16* ardp[4];
    const __bf16* brdp[4];
#pragma unroll
    for (int i = 0; i < 4; ++i) {
        ardp[i] = lsA + (wm * 64 + i * 16 + fr) * 32 + slot * 8;
        brdp[i] = lsB + (wn * 64 + i * 16 + fr) * 32 + slot * 8;
    }

    floatx4 acc[4][4];
    const floatx4 vzero = {0.f, 0.f, 0.f, 0.f};
#pragma unroll
    for (int mi = 0; mi < 4; ++mi)
#pragma unroll
        for (int ni = 0; ni < 4; ++ni) acc[mi][ni] = vzero;

    for (int kt = 0; kt < K; kt += 32) {
        __syncthreads();                       // previous tile's ds_reads done
#pragma unroll
        for (int t = 0; t < 4; ++t) {
            load_lds16((const void*)gsrc[t], (void*)ldst[t]);
            gsrc[t] += 32;
        }
        __syncthreads();                       // drains vmcnt -> LDS visible
        bf16x8 af[4], bf[4];
#pragma unroll
        for (int i = 0; i < 4; ++i) af[i] = *(const bf16x8*)ardp[i];
#pragma unroll
        for (int i = 0; i < 4; ++i) bf[i] = *(const bf16x8*)brdp[i];
#pragma unroll
        for (int mi = 0; mi < 4; ++mi)
#pragma unroll
            for (int ni = 0; ni < 4; ++ni)
                acc[mi][ni] = __builtin_amdgcn_mfma_f32_16x16x32_bf16(
                    af[mi], bf[ni], acc[mi][ni], 0, 0, 0);
    }

    // ---- epilogue. C/D layout: col = lane&15, row = (lane>>4)*4 + reg.
    const int cn  = lane & 15;
    const int cr4 = (lane >> 4) * 4;
#pragma unroll
    for (int ni = 0; ni < 4; ++ni) {
        int col = bn * 128 + wn * 64 + ni * 16 + cn;
        float bv = bias[col];
#pragma unroll
        for (int mi = 0; mi < 4; ++mi) {
            int row0 = bm * 128 + wm * 64 + mi * 16 + cr4;
#pragma unroll
            for (int q = 0; q < 4; ++q) {
                float v = acc[mi][ni][q] + bv;
                if (RELU) v = fmaxf(v, 0.f);
                if (OBF16) ((__bf16*)Cout)[(size_t)(row0 + q) * N + col] = (__bf16)v;
                else       ((float*)Cout)[(size_t)(row0 + q) * N + col] = v;
            }
        }
    }
}

// ---------------------------------------------------------------------------
// Fused logp + 126-step log-semiring 4x4 chain, in log2 domain (v_exp_f32 is
// native 2^x). 32 batches/block, 4 threads/batch (thread r holds row r of the
// running matrix M). theta[b,i,{mu,alpha},r,c] staged per step via float4.
// ---------------------------------------------------------------------------
__global__ __launch_bounds__(128)
void chain_kernel(const float* __restrict__ theta,  // [8192,4096]
                  const float* __restrict__ x,      // [8192,128]
                  float* __restrict__ out)          // [8192]
{
    __shared__ __align__(16) float th[32 * 36];   // 32 floats/batch, pad->36
    __shared__ __align__(16) float Ls[32 * 20];   // 16 floats/batch, pad->20
    const int tid = threadIdx.x;
    const int lb  = tid >> 2;      // 0..31
    const int r   = tid & 3;
    const int b   = blockIdx.x * 32 + lb;
    const size_t tbase = (size_t)b * 4096;

    const float LOG2E = 1.4426950408889634f;
    const float LN2   = 0.6931471805599453f;
    const float C0    = 2.3052328943245633f;   // 0.5*log(2pi) + log(4)

    float M[4];   // M[k] = running matrix row r, column k (log2 units)
#pragma unroll
    for (int k = 0; k < 4; ++k) M[k] = (k == r) ? 0.f : -1e30f;  // log identity

    for (int i = 1; i <= 126; ++i) {
        __syncthreads();                       // previous step's Ls reads done
        // stage theta[b, i*32 .. +32): thread r loads 8 floats
        floatx4 t0 = *(const floatx4*)(theta + tbase + i * 32 + r * 8);
        floatx4 t1 = *(const floatx4*)(theta + tbase + i * 32 + r * 8 + 4);
        *(floatx4*)&th[lb * 36 + r * 8]     = t0;
        *(floatx4*)&th[lb * 36 + r * 8 + 4] = t1;
        __syncthreads();
        // logp row r (log2 units): mu = th[0..15], alpha = th[16..31]
        float xv = x[b * 128 + i];
        floatx4 mu = *(const floatx4*)&th[lb * 36 + r * 4];
        floatx4 al = *(const floatx4*)&th[lb * 36 + 16 + r * 4];
        floatx4 lp;
#pragma unroll
        for (int c = 0; c < 4; ++c) {
            float e = fexp2(-al[c] * LOG2E);
            float z = (xv - mu[c]) * e;
            lp[c] = (-0.5f * z * z - al[c] - C0) * LOG2E;
        }
        *(floatx4*)&Ls[lb * 20 + r * 4] = lp;
        __syncthreads();
        floatx4 L0 = *(const floatx4*)&Ls[lb * 20 + 0];
        floatx4 L1 = *(const floatx4*)&Ls[lb * 20 + 4];
        floatx4 L2 = *(const floatx4*)&Ls[lb * 20 + 8];
        floatx4 L3 = *(const floatx4*)&Ls[lb * 20 + 12];
        float Mn[4];
#pragma unroll
        for (int c = 0; c < 4; ++c) {
            float a0 = M[0] + L0[c];
            float a1 = M[1] + L1[c];
            float a2 = M[2] + L2[c];
            float a3 = M[3] + L3[c];
            float mx = fmaxf(fmaxf(a0, a1), fmaxf(a2, a3));
            float s = fexp2(a0 - mx) + fexp2(a1 - mx) + fexp2(a2 - mx) + fexp2(a3 - mx);
            Mn[c] = mx + flog2(s);
        }
#pragma unroll
        for (int k = 0; k < 4; ++k) M[k] = Mn[k];
    }

    // t[r] = lse_c(M[r][c] + last[c]),  last[c] = logp[b,127,c,0]
    float xl = x[b * 128 + 127];
    float a[4];
#pragma unroll
    for (int c = 0; c < 4; ++c) {
        float mu_ = theta[tbase + 4064 + c * 4];
        float al_ = theta[tbase + 4064 + 16 + c * 4];
        float e = fexp2(-al_ * LOG2E);
        float z = (xl - mu_) * e;
        float lp2 = (-0.5f * z * z - al_ - C0) * LOG2E;
        a[c] = M[c] + lp2;
    }
    float mx = fmaxf(fmaxf(a[0], a[1]), fmaxf(a[2], a[3]));
    float tr = mx + flog2(fexp2(a[0] - mx) + fexp2(a[1] - mx) +
                          fexp2(a[2] - mx) + fexp2(a[3] - mx));

    // out = lse_r(first[r] + t[r]),  first[r] = logp[b,0,0,r]
    float x0  = x[b * 128];
    float muf = theta[tbase + r];
    float alf = theta[tbase + 16 + r];
    float ef = fexp2(-alf * LOG2E);
    float zf = (x0 - muf) * ef;
    float f2 = (-0.5f * zf * zf - alf - C0) * LOG2E;
    float v = f2 + tr;
    float m1 = fmaxf(v, __shfl_xor(v, 1));
    float m2 = fmaxf(m1, __shfl_xor(m1, 2));
    float s = fexp2(v - m2);
    s += __shfl_xor(s, 1);
    s += __shfl_xor(s, 2);
    if (r == 0) out[b] = (m2 + flog2(s)) * LN2;
}

// ---------------------------------------------------------------------------
extern "C" void kernel_launch(void* const* d_in, const int* in_sizes, int n_in,
                              void* d_out, int out_size, void* d_ws, size_t ws_size,
                              hipStream_t stream)
{
    (void)in_sizes; (void)n_in; (void)out_size; (void)ws_size;
    const float* x  = (const float*)d_in[0];
    const float* W0 = (const float*)d_in[1];
    const float* b0 = (const float*)d_in[2];
    const float* W1 = (const float*)d_in[3];
    const float* b1 = (const float*)d_in[4];
    const float* W2 = (const float*)d_in[5];
    const float* b2 = (const float*)d_in[6];
    const float* W3 = (const float*)d_in[7];
    const float* b3 = (const float*)d_in[8];

    char* ws = (char*)d_ws;
    size_t off = 0;
    auto alloc = [&](size_t bytes) { char* p = ws + off; off += bytes; return p; };
    __bf16* xb  = (__bf16*)alloc((size_t)8192 * 128 * 2);    // 2 MB
    __bf16* w0m = (__bf16*)alloc((size_t)2048 * 128 * 2);    // 0.5 MB
    __bf16* w1m = (__bf16*)alloc((size_t)2048 * 2048 * 2);   // 8 MB
    __bf16* w2m = (__bf16*)alloc((size_t)2048 * 2048 * 2);   // 8 MB
    __bf16* w3m = (__bf16*)alloc((size_t)4096 * 2048 * 2);   // 16 MB
    __bf16* h1  = (__bf16*)alloc((size_t)8192 * 2048 * 2);   // 32 MB
    __bf16* h2  = (__bf16*)alloc((size_t)8192 * 2048 * 2);   // 32 MB
    float*  th  = (float*) alloc((size_t)8192 * 4096 * 4);   // 128 MB
    __bf16* h3  = h1;   // h1 dead after GEMM2; reuse for h3  (total ~226.5 MB)

    // masked bf16 weights + bf16 x
    prep_w<<<(8192 * 128) / 256,  256, 0, stream>>>(x,  xb,  7, 3);
    prep_w<<<(2048 * 128) / 256,  256, 0, stream>>>(W0, w0m, 7, 0);
    prep_w<<<(2048 * 2048) / 256, 256, 0, stream>>>(W1, w1m, 11, 1);
    prep_w<<<(2048 * 2048) / 256, 256, 0, stream>>>(W2, w2m, 11, 1);
    prep_w<<<(4096 * 2048) / 256, 256, 0, stream>>>(W3, w3m, 11, 2);

    // 4 GEMMs: C[8192,N] = A * W^T + b
    gemm_bt<true,  true ><<<dim3(64, 16), 256, 0, stream>>>(xb, w0m, b0, h1, 2048, 128);
    gemm_bt<true,  true ><<<dim3(64, 16), 256, 0, stream>>>(h1, w1m, b1, h2, 2048, 2048);
    gemm_bt<true,  true ><<<dim3(64, 16), 256, 0, stream>>>(h2, w2m, b2, h3, 2048, 2048);
    gemm_bt<false, false><<<dim3(64, 32), 256, 0, stream>>>(h3, w3m, b3, th, 4096, 2048);

    // fused logp + log-matmul chain
    chain_kernel<<<8192 / 32, 128, 0, stream>>>(th, x, (float*)d_out);
}

// Round 2
// 471.553 us; speedup vs baseline: 1.1344x; 1.1344x over previous
//
#include <hip/hip_runtime.h>
#include <hip/hip_bf16.h>
#include <cstdint>
#include <cstddef>

#define AS1 __attribute__((address_space(1)))
#define AS3 __attribute__((address_space(3)))

typedef __bf16 bf16x8 __attribute__((ext_vector_type(8)));
typedef float  floatx4 __attribute__((ext_vector_type(4)));

__device__ __forceinline__ void load_lds16(const void* g, void* l) {
    // async global->LDS, 16B/lane; LDS dest is wave-uniform base + lane*16
    __builtin_amdgcn_global_load_lds((AS1 void*)g, (AS3 void*)l, 16, 0, 0);
}

__device__ __forceinline__ float fexp2(float x) { return __builtin_amdgcn_exp2f(x); }
__device__ __forceinline__ float flog2(float x) { return __builtin_amdgcn_logf(x); }

// ---------------------------------------------------------------------------
// Prep: apply MADE mask + convert fp32 -> bf16.
// mode 0: W0  keep = (row%127 >= col)
// mode 1: W1/W2 keep = (row%127 >= col%127)
// mode 2: W3  keep = ((row>>5) > col%127)
// mode 3: plain copy (x)
// ---------------------------------------------------------------------------
__global__ void prep_w(const float* __restrict__ W, __bf16* __restrict__ out,
                       int shift, int mode) {
    int idx = blockIdx.x * 256 + threadIdx.x;
    int row = idx >> shift;
    int col = idx & ((1 << shift) - 1);
    float v = W[idx];
    bool keep = true;
    if (mode == 0)      keep = (row % 127) >= col;
    else if (mode == 1) keep = (row % 127) >= (col % 127);
    else if (mode == 2) keep = (row >> 5) > (col % 127);
    out[idx] = (__bf16)(keep ? v : 0.0f);
}

// ---------------------------------------------------------------------------
// bf16 MFMA GEMM, C[M,N] = A[M,K] * Bw[N,K]^T + bias, optional ReLU.
// 128x128 tile, BK=32, 4 waves (2x2 of 64x64), 16x16x32 MFMA 4x4 per wave.
// global_load_lds width=16 staging, XOR-swizzled LDS 16B slots.
// ---------------------------------------------------------------------------
template <bool RELU, bool OBF16>
__global__ __launch_bounds__(256, 2)
void gemm_bt(const __bf16* __restrict__ A, const __bf16* __restrict__ Bw,
             const float* __restrict__ bias, void* __restrict__ Cout,
             int N, int K)
{
    __shared__ __align__(16) __bf16 lsA[128 * 32];
    __shared__ __align__(16) __bf16 lsB[128 * 32];
    const int tid  = threadIdx.x;
    const int wave = tid >> 6;
    const int lane = tid & 63;
    const int bm = blockIdx.x, bn = blockIdx.y;
    const int wm = wave >> 1, wn = wave & 1;

    const int rsub = lane >> 2;
    const int cbx  = (lane & 3) ^ ((lane >> 3) & 3);
    const __bf16* gsrc[4];
    __bf16* ldst[4];
#pragma unroll
    for (int t = 0; t < 4; ++t) {
        int j = wave * 4 + t;
        if (j < 8) {
            int row = bm * 128 + j * 16 + rsub;
            gsrc[t] = A + (size_t)row * K + cbx * 8;
            ldst[t] = lsA + j * 512;
        } else {
            int jj = j - 8;
            int row = bn * 128 + jj * 16 + rsub;
            gsrc[t] = Bw + (size_t)row * K + cbx * 8;
            ldst[t] = lsB + jj * 512;
        }
    }

    const int fr   = lane & 15;
    const int ks   = lane >> 4;
    const int slot = ks ^ ((fr >> 1) & 3);
    const __bf16* ardp[4];
    const __bf16* brdp[4];
#pragma unroll
    for (int i = 0; i < 4; ++i) {
        ardp[i] = lsA + (wm * 64 + i * 16 + fr) * 32 + slot * 8;
        brdp[i] = lsB + (wn * 64 + i * 16 + fr) * 32 + slot * 8;
    }

    floatx4 acc[4][4];
    const floatx4 vzero = {0.f, 0.f, 0.f, 0.f};
#pragma unroll
    for (int mi = 0; mi < 4; ++mi)
#pragma unroll
        for (int ni = 0; ni < 4; ++ni) acc[mi][ni] = vzero;

    for (int kt = 0; kt < K; kt += 32) {
        __syncthreads();
#pragma unroll
        for (int t = 0; t < 4; ++t) {
            load_lds16((const void*)gsrc[t], (void*)ldst[t]);
            gsrc[t] += 32;
        }
        __syncthreads();
        bf16x8 af[4], bf[4];
#pragma unroll
        for (int i = 0; i < 4; ++i) af[i] = *(const bf16x8*)ardp[i];
#pragma unroll
        for (int i = 0; i < 4; ++i) bf[i] = *(const bf16x8*)brdp[i];
#pragma unroll
        for (int mi = 0; mi < 4; ++mi)
#pragma unroll
            for (int ni = 0; ni < 4; ++ni)
                acc[mi][ni] = __builtin_amdgcn_mfma_f32_16x16x32_bf16(
                    af[mi], bf[ni], acc[mi][ni], 0, 0, 0);
    }

    const int cn  = lane & 15;
    const int cr4 = (lane >> 4) * 4;
#pragma unroll
    for (int ni = 0; ni < 4; ++ni) {
        int col = bn * 128 + wn * 64 + ni * 16 + cn;
        float bv = bias[col];
#pragma unroll
        for (int mi = 0; mi < 4; ++mi) {
            int row0 = bm * 128 + wm * 64 + mi * 16 + cr4;
#pragma unroll
            for (int q = 0; q < 4; ++q) {
                float v = acc[mi][ni][q] + bv;
                if (RELU) v = fmaxf(v, 0.f);
                if (OBF16) ((__bf16*)Cout)[(size_t)(row0 + q) * N + col] = (__bf16)v;
                else       ((float*)Cout)[(size_t)(row0 + q) * N + col] = v;
            }
        }
    }
}

// ---------------------------------------------------------------------------
// Segment-parallel log-semiring chain. 126 interior steps = 9 segments x 14.
// One 4-lane group per (batch, segment); lane r holds row r of the running
// 4x4 matrix in log2 domain. Row exchange via intra-wave shuffles (no LDS,
// no barriers). Writes P[b][s][16].
// ---------------------------------------------------------------------------
__global__ __launch_bounds__(256)
void chain_seg(const float* __restrict__ theta,  // [8192,4096]
               const float* __restrict__ x,      // [8192,128]
               float* __restrict__ P)            // [8192,9,16]
{
    const int tid  = threadIdx.x;
    const int lane = tid & 63;
    const int r    = lane & 3;
    const int l0   = lane & 60;                 // group base lane in wave
    const int b    = blockIdx.x * 64 + (tid >> 2);
    const int s    = blockIdx.y;                // 0..8
    const size_t tbase = (size_t)b * 4096;
    const int i0 = 1 + s * 14;

    const float LOG2E = 1.4426950408889634f;
    const float C0    = 2.3052328943245633f;   // 0.5*log(2pi) + log(4)

    float M[4];
#pragma unroll
    for (int k = 0; k < 4; ++k) M[k] = (k == r) ? 0.f : -1e30f;

    const float* mup = theta + tbase + (size_t)i0 * 32 + r * 4;
    const float* xp  = x + (size_t)b * 128 + i0;

    for (int ii = 0; ii < 14; ++ii) {
        floatx4 mu = *(const floatx4*)(mup);
        floatx4 al = *(const floatx4*)(mup + 16);
        float xv = xp[ii];
        mup += 32;
        floatx4 lp;
#pragma unroll
        for (int c = 0; c < 4; ++c) {
            float e = fexp2(-al[c] * LOG2E);
            float z = (xv - mu[c]) * e;
            lp[c] = (-0.5f * z * z - al[c] - C0) * LOG2E;
        }
        float Mn[4];
#pragma unroll
        for (int c = 0; c < 4; ++c) {
            float a0 = M[0] + __shfl(lp[c], l0 + 0);
            float a1 = M[1] + __shfl(lp[c], l0 + 1);
            float a2 = M[2] + __shfl(lp[c], l0 + 2);
            float a3 = M[3] + __shfl(lp[c], l0 + 3);
            float mx = fmaxf(fmaxf(a0, a1), fmaxf(a2, a3));
            float sm = fexp2(a0 - mx) + fexp2(a1 - mx) + fexp2(a2 - mx) + fexp2(a3 - mx);
            Mn[c] = mx + flog2(sm);
        }
#pragma unroll
        for (int k = 0; k < 4; ++k) M[k] = Mn[k];
    }

    floatx4 o = {M[0], M[1], M[2], M[3]};
    *(floatx4*)(P + ((size_t)b * 9 + s) * 16 + r * 4) = o;
}

// ---------------------------------------------------------------------------
// Combine: fold 9 segment matrices + first/last boundary vectors per batch.
// ---------------------------------------------------------------------------
__global__ __launch_bounds__(256)
void chain_fin(const float* __restrict__ theta,  // [8192,4096]
               const float* __restrict__ x,      // [8192,128]
               const float* __restrict__ P,      // [8192,9,16]
               float* __restrict__ out)          // [8192]
{
    const int tid  = threadIdx.x;
    const int lane = tid & 63;
    const int r    = lane & 3;
    const int l0   = lane & 60;
    const int b    = blockIdx.x * 64 + (tid >> 2);
    const size_t tbase = (size_t)b * 4096;

    const float LOG2E = 1.4426950408889634f;
    const float LN2   = 0.6931471805599453f;
    const float C0    = 2.3052328943245633f;

    const float* Pb = P + (size_t)b * 144;
    floatx4 m0 = *(const floatx4*)(Pb + r * 4);
    float M[4] = {m0[0], m0[1], m0[2], m0[3]};

#pragma unroll
    for (int s = 1; s < 9; ++s) {
        floatx4 lr = *(const floatx4*)(Pb + s * 16 + r * 4);
        float Mn[4];
#pragma unroll
        for (int c = 0; c < 4; ++c) {
            float a0 = M[0] + __shfl(lr[c], l0 + 0);
            float a1 = M[1] + __shfl(lr[c], l0 + 1);
            float a2 = M[2] + __shfl(lr[c], l0 + 2);
            float a3 = M[3] + __shfl(lr[c], l0 + 3);
            float mx = fmaxf(fmaxf(a0, a1), fmaxf(a2, a3));
            float sm = fexp2(a0 - mx) + fexp2(a1 - mx) + fexp2(a2 - mx) + fexp2(a3 - mx);
            Mn[c] = mx + flog2(sm);
        }
#pragma unroll
        for (int k = 0; k < 4; ++k) M[k] = Mn[k];
    }

    // t[r] = lse_c(M[r][c] + last[c]),  last[c] = logp[b,127,c,0]
    float xl = x[(size_t)b * 128 + 127];
    float a[4];
#pragma unroll
    for (int c = 0; c < 4; ++c) {
        float mu_ = theta[tbase + 4064 + c * 4];
        float al_ = theta[tbase + 4064 + 16 + c * 4];
        float e = fexp2(-al_ * LOG2E);
        float z = (xl - mu_) * e;
        float lp2 = (-0.5f * z * z - al_ - C0) * LOG2E;
        a[c] = M[c] + lp2;
    }
    float mx = fmaxf(fmaxf(a[0], a[1]), fmaxf(a[2], a[3]));
    float tr = mx + flog2(fexp2(a[0] - mx) + fexp2(a[1] - mx) +
                          fexp2(a[2] - mx) + fexp2(a[3] - mx));

    // out = lse_r(first[r] + t[r]),  first[r] = logp[b,0,0,r]
    float x0  = x[(size_t)b * 128];
    float muf = theta[tbase + r];
    float alf = theta[tbase + 16 + r];
    float ef = fexp2(-alf * LOG2E);
    float zf = (x0 - muf) * ef;
    float f2 = (-0.5f * zf * zf - alf - C0) * LOG2E;
    float v = f2 + tr;
    float m1 = fmaxf(v, __shfl_xor(v, 1));
    float m2 = fmaxf(m1, __shfl_xor(m1, 2));
    float sum = fexp2(v - m2);
    sum += __shfl_xor(sum, 1);
    sum += __shfl_xor(sum, 2);
    if (r == 0) out[b] = (m2 + flog2(sum)) * LN2;
}

// ---------------------------------------------------------------------------
extern "C" void kernel_launch(void* const* d_in, const int* in_sizes, int n_in,
                              void* d_out, int out_size, void* d_ws, size_t ws_size,
                              hipStream_t stream)
{
    (void)in_sizes; (void)n_in; (void)out_size; (void)ws_size;
    const float* x  = (const float*)d_in[0];
    const float* W0 = (const float*)d_in[1];
    const float* b0 = (const float*)d_in[2];
    const float* W1 = (const float*)d_in[3];
    const float* b1 = (const float*)d_in[4];
    const float* W2 = (const float*)d_in[5];
    const float* b2 = (const float*)d_in[6];
    const float* W3 = (const float*)d_in[7];
    const float* b3 = (const float*)d_in[8];

    char* ws = (char*)d_ws;
    size_t off = 0;
    auto alloc = [&](size_t bytes) { char* p = ws + off; off += bytes; return p; };
    __bf16* xb  = (__bf16*)alloc((size_t)8192 * 128 * 2);    // 2 MB
    __bf16* w0m = (__bf16*)alloc((size_t)2048 * 128 * 2);    // 0.5 MB
    __bf16* w1m = (__bf16*)alloc((size_t)2048 * 2048 * 2);   // 8 MB
    __bf16* w2m = (__bf16*)alloc((size_t)2048 * 2048 * 2);   // 8 MB
    __bf16* w3m = (__bf16*)alloc((size_t)4096 * 2048 * 2);   // 16 MB
    __bf16* h1  = (__bf16*)alloc((size_t)8192 * 2048 * 2);   // 32 MB
    __bf16* h2  = (__bf16*)alloc((size_t)8192 * 2048 * 2);   // 32 MB
    float*  th  = (float*) alloc((size_t)8192 * 4096 * 4);   // 128 MB
    __bf16* h3  = h1;            // h1 dead after GEMM2; reuse for h3
    float*  P   = (float*)h2;    // h2 dead after GEMM3 input read ordering:
                                 // chain_seg runs after GEMM3; P = 4.7 MB << 32 MB

    // masked bf16 weights + bf16 x
    prep_w<<<(8192 * 128) / 256,  256, 0, stream>>>(x,  xb,  7, 3);
    prep_w<<<(2048 * 128) / 256,  256, 0, stream>>>(W0, w0m, 7, 0);
    prep_w<<<(2048 * 2048) / 256, 256, 0, stream>>>(W1, w1m, 11, 1);
    prep_w<<<(2048 * 2048) / 256, 256, 0, stream>>>(W2, w2m, 11, 1);
    prep_w<<<(4096 * 2048) / 256, 256, 0, stream>>>(W3, w3m, 11, 2);

    // 4 GEMMs: C[8192,N] = A * W^T + b
    gemm_bt<true,  true ><<<dim3(64, 16), 256, 0, stream>>>(xb, w0m, b0, h1, 2048, 128);
    gemm_bt<true,  true ><<<dim3(64, 16), 256, 0, stream>>>(h1, w1m, b1, h2, 2048, 2048);
    gemm_bt<true,  true ><<<dim3(64, 16), 256, 0, stream>>>(h2, w2m, b2, h3, 2048, 2048);
    gemm_bt<false, false><<<dim3(64, 32), 256, 0, stream>>>(h3, w3m, b3, th, 4096, 2048);

    // segment-parallel log-semiring chain
    chain_seg<<<dim3(128, 9), 256, 0, stream>>>(th, x, P);
    chain_fin<<<128, 256, 0, stream>>>(th, x, P, (float*)d_out);
}